// Round 1
// baseline (283.376 us; speedup 1.0000x reference)
//
#include <hip/hip_runtime.h>
#include <hip/hip_bf16.h>

// LorentzEquivariantAdapter fused kernel, MI355X gfx950. Round 3.
// Key changes vs R2:
//  - 1024 blocks x 2 chunks of 16 tokens (32 consecutive tokens per block).
//    Chunk 1's x-tile (16 float4/thread = 64 VGPR) is register-prefetched
//    during chunk 0's compute -> HBM fetch duty cycle ~2x (was 27% busy).
//  - All __syncthreads() replaced by non-draining barriers
//    (s_waitcnt lgkmcnt(0) + raw s_barrier): cross-wave traffic is LDS-only,
//    so the compiler's vmcnt(0) drain at barriers is pure stall AND would
//    kill the prefetch. Global loads are thread-private; stores never read.
//  - Everything else (LN-folded GEMM1, LDS aliasing, layouts) unchanged.

typedef __attribute__((ext_vector_type(8))) short short8;   // 8 bf16 = one MFMA A/B fragment
typedef __attribute__((ext_vector_type(4))) short short4b;  // 4 bf16 = 8B store
typedef __attribute__((ext_vector_type(4))) float float4a;  // MFMA accumulator

#define NTOK 32768
#define D 1024
#define NBLK 1024   // each block: 2 chunks of 16 tokens = 32 tokens

__device__ __forceinline__ short f2bf(float x) {
    unsigned u = __float_as_uint(x);
    unsigned r = u + 0x7FFFu + ((u >> 16) & 1u);   // RNE
    return (short)(r >> 16);
}
__device__ __forceinline__ float bf2f(short s) {
    return __uint_as_float(((unsigned)(unsigned short)s) << 16);
}
__device__ __forceinline__ float gelu_exact(float v) {
    return 0.5f * v * (1.0f + erff(v * 0.70710678118654752f));
}

// Non-draining workgroup barrier: orders LDS (lgkmcnt) but leaves global
// loads/stores (vmcnt) in flight across the barrier. Safe here: all
// cross-wave communication is through LDS; global accesses are either
// thread-private (x loads, consumed by issuing thread), read-only weights,
// or write-once outputs never read back.
__device__ __forceinline__ void bar_lds() {
    asm volatile("s_waitcnt lgkmcnt(0)" ::: "memory");
    __builtin_amdgcn_s_barrier();
    asm volatile("" ::: "memory");
}

// ---- weight prep ----
// blocks [0,192):   wdn_b = bf16(gamma[d] * w_down[r][d]) in MFMA B-fragment order
// blocks [192,448): wup_b = bf16(w_up[d][r]) in MFMA B-fragment order, K padded 48->64
// blocks [448,496): c12[r] = sum_d gamma[d]*w_down[r][d];  c12[48+r] = sum_d beta[d]*w_down[r][d]
__global__ void prep_weights(const float* __restrict__ wdn_f, const float* __restrict__ wup_f,
                             const float* __restrict__ gamma, const float* __restrict__ beta,
                             short* __restrict__ wdn_b, short* __restrict__ wup_b,
                             float* __restrict__ c12) {
    int blk = blockIdx.x;
    int tid = threadIdx.x;
    if (blk < 192) {
        int o = blk * 256 + tid;
        int j = o & 7, lane = (o >> 3) & 63, kt = (o >> 9) & 31, cb = o >> 14;
        int r = cb * 16 + (lane & 15);
        int d = kt * 32 + (lane >> 4) * 8 + j;
        wdn_b[o] = f2bf(wdn_f[r * 1024 + d] * gamma[d]);
    } else if (blk < 448) {
        int o2 = (blk - 192) * 256 + tid;
        int j = o2 & 7, lane = (o2 >> 3) & 63, kt = (o2 >> 9) & 1, cb = o2 >> 10;
        int dcol = cb * 16 + (lane & 15);
        int r = kt * 32 + (lane >> 4) * 8 + j;
        wup_b[o2] = (r < 48) ? f2bf(wup_f[dcol * 48 + r]) : (short)0;
    } else {
        int r = blk - 448;                       // 0..47
        float a = 0.f, b = 0.f;
#pragma unroll
        for (int i = 0; i < 4; ++i) {
            int d = tid + 256 * i;
            float wv = wdn_f[r * 1024 + d];
            a = fmaf(wv, gamma[d], a);
            b = fmaf(wv, beta[d], b);
        }
#pragma unroll
        for (int off = 32; off; off >>= 1) {
            a += __shfl_xor(a, off);
            b += __shfl_xor(b, off);
        }
        __shared__ float red[8];
        int lane = tid & 63, w = tid >> 6;
        if (lane == 0) { red[w] = a; red[4 + w] = b; }
        __syncthreads();
        if (tid == 0) {
            c12[r]      = red[0] + red[1] + red[2] + red[3];
            c12[48 + r] = red[4] + red[5] + red[6] + red[7];
        }
    }
}

__launch_bounds__(256, 4)
__global__ void adapter_main(const float* __restrict__ x, const float* __restrict__ w_to_mv,
                             const float* __restrict__ w_equi, const float* __restrict__ b_equi,
                             const float* __restrict__ w_from_mv, const float* __restrict__ scale_p,
                             const short* __restrict__ wdn_b, const short* __restrict__ wup_b,
                             const float* __restrict__ c12, float* __restrict__ out) {
    // LDS total = 33024 + 6272 = 39296 B -> 4 blocks/CU
    __shared__ __align__(16) short xsh[16][1032];   // x as bf16, pad +8 shorts (A-fragment b128 reads)
    __shared__ __align__(16) float scratch[1568];
    // scratch layout (phase-aliased):
    //   [0..767]     ypart[0][tok][r]  ->  ybuf(gelu)  ->  zbuf shorts [0..1023] (=floats [0..511])
    //   [768..1535]  ypart[1][tok][r]  ->  mvbuf[tok][16] (floats [768..1023])
    //   [1536..1551] rs[tok]   [1552..1567] -mu*rs[tok]
    short* zbuf = (short*)scratch;

    const int tid  = threadIdx.x;
    const int lane = tid & 63;
    const int w    = tid >> 6;          // wave id 0..3
    const int q    = lane >> 4;         // MFMA quad
    const int m    = lane & 15;         // MFMA row/col within tile
    const long tokbase = (long)blockIdx.x * 32;
    const float scale = scale_p[0];

    // initial load: chunk 0 (16 tokens), 16 float4/thread
    const float4* xr = (const float4*)(x + tokbase * D);
    float4 v[16];
#pragma unroll
    for (int t = 0; t < 4; ++t)
#pragma unroll
        for (int i = 0; i < 4; ++i)
            v[t * 4 + i] = xr[(w * 4 + t) * 256 + lane + 64 * i];

#pragma unroll
    for (int c = 0; c < 2; ++c) {
        const long token0 = tokbase + c * 16;

        // ---------------- Phase 0: stats, x->bf16 LDS (from registers) ----------------
#pragma unroll
        for (int t = 0; t < 4; ++t) {
            int tok = w * 4 + t;
            float s1 = 0.f, s2 = 0.f;
#pragma unroll
            for (int i = 0; i < 4; ++i) {
                float4 vv = v[t * 4 + i];
                s1 += vv.x + vv.y + vv.z + vv.w;
                s2 += vv.x * vv.x + vv.y * vv.y + vv.z * vv.z + vv.w * vv.w;
            }
#pragma unroll
            for (int off = 32; off; off >>= 1) {
                s1 += __shfl_xor(s1, off);
                s2 += __shfl_xor(s2, off);
            }
            float mu  = s1 * (1.0f / 1024.0f);
            float var = fmaf(-mu, mu, s2 * (1.0f / 1024.0f));
            float rs  = rsqrtf(var + 1e-5f);
#pragma unroll
            for (int i = 0; i < 4; ++i) {
                int d0 = 4 * lane + 256 * i;
                float4 vv = v[t * 4 + i];
                short4b xs = {f2bf(vv.x), f2bf(vv.y), f2bf(vv.z), f2bf(vv.w)};
                *(short4b*)&xsh[tok][d0] = xs;
            }
            if (lane == 0) {
                scratch[1536 + tok] = rs;
                scratch[1552 + tok] = -mu * rs;
            }
        }

        // ---------------- Prefetch chunk 1's x while chunk 0 computes ----------------
        // Issued before the barrier below; bar_lds does NOT drain vmcnt, so
        // these 16 loads stay in flight across GEMM1/middle/GEMM2.
        float4 vn[16];
        if (c == 0) {
            const float4* xr2 = (const float4*)(x + (tokbase + 16) * D);
#pragma unroll
            for (int t = 0; t < 4; ++t)
#pragma unroll
                for (int i = 0; i < 4; ++i)
                    vn[t * 4 + i] = xr2[(w * 4 + t) * 256 + lane + 64 * i];
        }
        bar_lds();

        // ---------------- GEMM1: ypart = x_bf16 @ (gamma*w_down)^T, K split in halves ----------------
#pragma unroll
        for (int rep = 0; rep < 2; ++rep) {
            int jid = w + rep * 4;
            if (jid < 6) {
                int cb = jid % 3, kh = jid / 3;
                float4a acc = {0.f, 0.f, 0.f, 0.f};
                const short* bptr = wdn_b + ((cb * 32 + kh * 16) * 64 + lane) * 8;
                const short* aptr = &xsh[m][kh * 512 + q * 8];
#pragma unroll
                for (int kt = 0; kt < 16; ++kt) {
                    short8 a = *(const short8*)(aptr + kt * 32);
                    short8 b = *(const short8*)(bptr + kt * 512);
                    acc = __builtin_amdgcn_mfma_f32_16x16x32_bf16(a, b, acc, 0, 0, 0);
                }
#pragma unroll
                for (int i = 0; i < 4; ++i)
                    scratch[kh * 768 + (q * 4 + i) * 48 + cb * 16 + m] = acc[i];
            }
        }
        bar_lds();

        // ---------------- Middle (fp32 VALU) ----------------
        // A: K-half reduce + LN affine correction + exact GELU (in place in ypart[0])
#pragma unroll
        for (int k = 0; k < 3; ++k) {
            int it = tid + k * 256;               // 768 = 16 tok x 48 r
            int tt = it / 48, r = it - tt * 48;
            float s = scratch[tt * 48 + r] + scratch[768 + tt * 48 + r];
            float y = fmaf(scratch[1536 + tt], s, fmaf(scratch[1552 + tt], c12[r], c12[48 + r]));
            scratch[tt * 48 + r] = gelu_exact(y);
        }
        bar_lds();
        // B: multivectors + grade scale + scalar bias -> mvbuf (scratch[768..1023])
        {
            int tt = tid >> 4, j = tid & 15;
            float acc = 0.f;
#pragma unroll 8
            for (int r = 0; r < 48; ++r) acc = fmaf(w_to_mv[j * 48 + r], scratch[tt * 48 + r], acc);
            int g = (j == 0) ? 0 : (j < 5) ? 1 : (j < 11) ? 2 : (j < 15) ? 3 : 4;
            acc *= w_equi[g];
            if (j == 0) acc += b_equi[0];
            scratch[768 + tt * 16 + j] = acc;
        }
        bar_lds();
        // C: z = gelu(mv @ w_from_mv^T) -> zbuf in GEMM2 A-fragment order (K padded 48->64)
#pragma unroll
        for (int k = 0; k < 3; ++k) {
            int it = tid + k * 256;
            int tt = it / 48, r = it - tt * 48;
            float acc = 0.f;
#pragma unroll
            for (int j = 0; j < 16; ++j) acc = fmaf(w_from_mv[r * 16 + j], scratch[768 + tt * 16 + j], acc);
            float z = gelu_exact(acc);
            int kt = r >> 5, qq = (r >> 3) & 3, jj = r & 7;
            zbuf[kt * 512 + (qq * 16 + tt) * 8 + jj] = f2bf(z);
        }
        zbuf[768 + tid] = 0;                      // K padding 48..63
        bar_lds();

        // ---------------- GEMM2 + epilogue: out = x + scale * (z @ w_up^T) ----------------
        short8 a0 = *(const short8*)&zbuf[lane * 8];
        short8 a1 = *(const short8*)&zbuf[512 + lane * 8];
        long rowbase = (token0 + q * 4) * D;
#pragma unroll 4
        for (int cc = 0; cc < 16; ++cc) {
            int cb = w * 16 + cc;
            short8 b0 = *(const short8*)(wup_b + (cb * 2 + 0) * 512 + lane * 8);
            short8 b1 = *(const short8*)(wup_b + (cb * 2 + 1) * 512 + lane * 8);
            float4a acc = {0.f, 0.f, 0.f, 0.f};
            acc = __builtin_amdgcn_mfma_f32_16x16x32_bf16(a0, b0, acc, 0, 0, 0);
            acc = __builtin_amdgcn_mfma_f32_16x16x32_bf16(a1, b1, acc, 0, 0, 0);
            int d = cb * 16 + m;
#pragma unroll
            for (int i = 0; i < 4; ++i) {
                int tok = q * 4 + i;
                float xv = bf2f(xsh[tok][d]);
                out[rowbase + (long)i * D + d] = fmaf(scale, acc[i], xv);
            }
        }

        // hand prefetched registers to the next chunk; barrier protects xsh reuse
        if (c == 0) {
            bar_lds();
#pragma unroll
            for (int i2 = 0; i2 < 16; ++i2) v[i2] = vn[i2];
        }
    }
}

extern "C" void kernel_launch(void* const* d_in, const int* in_sizes, int n_in,
                              void* d_out, int out_size, void* d_ws, size_t ws_size,
                              hipStream_t stream) {
    const float* x         = (const float*)d_in[0];
    const float* gamma     = (const float*)d_in[1];
    const float* beta      = (const float*)d_in[2];
    const float* w_down    = (const float*)d_in[3];
    const float* w_to_mv   = (const float*)d_in[4];
    const float* w_equi    = (const float*)d_in[5];
    const float* b_equi    = (const float*)d_in[6];
    const float* w_from_mv = (const float*)d_in[7];
    const float* w_up      = (const float*)d_in[8];
    const float* scale_p   = (const float*)d_in[9];

    short* wdn_b = (short*)d_ws;               // 49152 bf16
    short* wup_b = wdn_b + 49152;              // 65536 bf16 (K padded to 64)
    float* c12   = (float*)(wup_b + 65536);    // 96 fp32

    prep_weights<<<496, 256, 0, stream>>>(w_down, w_up, gamma, beta, wdn_b, wup_b, c12);
    adapter_main<<<NBLK, 256, 0, stream>>>(
        x, w_to_mv, w_equi, b_equi, w_from_mv, scale_p,
        wdn_b, wup_b, c12, (float*)d_out);
}

// Round 2
// 277.568 us; speedup vs baseline: 1.0209x; 1.0209x over previous
//
#include <hip/hip_runtime.h>
#include <hip/hip_bf16.h>

// LorentzEquivariantAdapter fused kernel, MI355X gfx950. Round 4.
// Post-mortem R3: register prefetch of chunk+1 (64 VGPR) blew the 128-reg cap
// -> scratch spills (VGPR=64 + 23MB extra HBM writes) -> regression. Reverted.
// R4 theory: R2 was HBM-duty-cycle-bound (27% busy): 4 phase-locked blocks/CU
// issue loads only in narrow phase-0 bursts. Fix occupancy, not pipelining:
//  - 8-token tiles: LDS 39.3KB -> 20.2KB  => 8 blocks/CU, 32 waves (100% cap)
//  - 4096 independent blocks, half-size bursts, natural desync -> higher duty
//  - __launch_bounds__(256,8) (VGPR cap 64; R2 ran at 52 with MORE pressure)
//  - non-draining barriers kept (LDS-only cross-wave traffic)
// MFMA M=8/16 rows wasted: irrelevant at 3% MfmaUtil.

typedef __attribute__((ext_vector_type(8))) short short8;   // 8 bf16 = one MFMA A/B fragment
typedef __attribute__((ext_vector_type(4))) short short4b;  // 4 bf16 = 8B store
typedef __attribute__((ext_vector_type(4))) float float4a;  // MFMA accumulator

#define NTOK 32768
#define D 1024
#define TOK 8
#define NBLK (NTOK / TOK)   // 4096

__device__ __forceinline__ short f2bf(float x) {
    unsigned u = __float_as_uint(x);
    unsigned r = u + 0x7FFFu + ((u >> 16) & 1u);   // RNE
    return (short)(r >> 16);
}
__device__ __forceinline__ float bf2f(short s) {
    return __uint_as_float(((unsigned)(unsigned short)s) << 16);
}
__device__ __forceinline__ float gelu_exact(float v) {
    return 0.5f * v * (1.0f + erff(v * 0.70710678118654752f));
}

// Non-draining workgroup barrier: orders LDS (lgkmcnt) but leaves global
// loads/stores (vmcnt) in flight. Safe: all cross-wave traffic is LDS-only;
// global accesses are thread-private loads, read-only weights, or
// write-once outputs never re-read.
__device__ __forceinline__ void bar_lds() {
    asm volatile("s_waitcnt lgkmcnt(0)" ::: "memory");
    __builtin_amdgcn_s_barrier();
    asm volatile("" ::: "memory");
}

// ---- weight prep ----
// blocks [0,192):   wdn_b = bf16(gamma[d] * w_down[r][d]) in MFMA B-fragment order
// blocks [192,448): wup_b = bf16(w_up[d][r]) in MFMA B-fragment order, K padded 48->64
// blocks [448,496): c12[r] = sum_d gamma[d]*w_down[r][d];  c12[48+r] = sum_d beta[d]*w_down[r][d]
__global__ void prep_weights(const float* __restrict__ wdn_f, const float* __restrict__ wup_f,
                             const float* __restrict__ gamma, const float* __restrict__ beta,
                             short* __restrict__ wdn_b, short* __restrict__ wup_b,
                             float* __restrict__ c12) {
    int blk = blockIdx.x;
    int tid = threadIdx.x;
    if (blk < 192) {
        int o = blk * 256 + tid;
        int j = o & 7, lane = (o >> 3) & 63, kt = (o >> 9) & 31, cb = o >> 14;
        int r = cb * 16 + (lane & 15);
        int d = kt * 32 + (lane >> 4) * 8 + j;
        wdn_b[o] = f2bf(wdn_f[r * 1024 + d] * gamma[d]);
    } else if (blk < 448) {
        int o2 = (blk - 192) * 256 + tid;
        int j = o2 & 7, lane = (o2 >> 3) & 63, kt = (o2 >> 9) & 1, cb = o2 >> 10;
        int dcol = cb * 16 + (lane & 15);
        int r = kt * 32 + (lane >> 4) * 8 + j;
        wup_b[o2] = (r < 48) ? f2bf(wup_f[dcol * 48 + r]) : (short)0;
    } else {
        int r = blk - 448;                       // 0..47
        float a = 0.f, b = 0.f;
#pragma unroll
        for (int i = 0; i < 4; ++i) {
            int d = tid + 256 * i;
            float wv = wdn_f[r * 1024 + d];
            a = fmaf(wv, gamma[d], a);
            b = fmaf(wv, beta[d], b);
        }
#pragma unroll
        for (int off = 32; off; off >>= 1) {
            a += __shfl_xor(a, off);
            b += __shfl_xor(b, off);
        }
        __shared__ float red[8];
        int lane = tid & 63, w = tid >> 6;
        if (lane == 0) { red[w] = a; red[4 + w] = b; }
        __syncthreads();
        if (tid == 0) {
            c12[r]      = red[0] + red[1] + red[2] + red[3];
            c12[48 + r] = red[4] + red[5] + red[6] + red[7];
        }
    }
}

__launch_bounds__(256, 8)
__global__ void adapter_main(const float* __restrict__ x, const float* __restrict__ w_to_mv,
                             const float* __restrict__ w_equi, const float* __restrict__ b_equi,
                             const float* __restrict__ w_from_mv, const float* __restrict__ scale_p,
                             const short* __restrict__ wdn_b, const short* __restrict__ wup_b,
                             const float* __restrict__ c12, float* __restrict__ out) {
    // LDS total = 16512 + 3648 = 20160 B -> 8 blocks/CU (8 x ~20.3KB <= 160KB)
    __shared__ __align__(16) short xsh[TOK][1032];  // x as bf16, pad +8 shorts (b128 A-reads)
    __shared__ __align__(16) float scratch[912];
    // scratch layout (floats, phase-aliased):
    //   [0..383]    ypart[0][tok][r] -> gelu(y) in place -> zbuf shorts [0..767]
    //   [384..767]  ypart[1][tok][r] -> zbuf shorts [768..1023] (K-pad zeros)
    //   [768..895]  mvbuf[tok][16]
    //   [896..903]  rs[tok]     [904..911]  -mu*rs[tok]
    short* zbuf = (short*)scratch;

    const int tid  = threadIdx.x;
    const int lane = tid & 63;
    const int w    = tid >> 6;          // wave id 0..3
    const int q    = lane >> 4;         // MFMA quad
    const int m    = lane & 15;         // MFMA row/col within tile
    const long token0 = (long)blockIdx.x * TOK;

    // ---------------- Phase 0: load x (8 float4/thread), stats, x->bf16 LDS ----------------
    {
        const float4* xr = (const float4*)(x + token0 * D);
        float4 v[8];
#pragma unroll
        for (int t = 0; t < 2; ++t)
#pragma unroll
            for (int i = 0; i < 4; ++i)
                v[t * 4 + i] = xr[(w * 2 + t) * 256 + lane + 64 * i];

#pragma unroll
        for (int t = 0; t < 2; ++t) {
            int tok = w * 2 + t;
            float s1 = 0.f, s2 = 0.f;
#pragma unroll
            for (int i = 0; i < 4; ++i) {
                float4 vv = v[t * 4 + i];
                s1 += vv.x + vv.y + vv.z + vv.w;
                s2 += vv.x * vv.x + vv.y * vv.y + vv.z * vv.z + vv.w * vv.w;
            }
#pragma unroll
            for (int off = 32; off; off >>= 1) {
                s1 += __shfl_xor(s1, off);
                s2 += __shfl_xor(s2, off);
            }
            float mu  = s1 * (1.0f / 1024.0f);
            float var = fmaf(-mu, mu, s2 * (1.0f / 1024.0f));
            float rs  = rsqrtf(var + 1e-5f);
#pragma unroll
            for (int i = 0; i < 4; ++i) {
                int d0 = 4 * lane + 256 * i;
                float4 vv = v[t * 4 + i];
                short4b xs = {f2bf(vv.x), f2bf(vv.y), f2bf(vv.z), f2bf(vv.w)};
                *(short4b*)&xsh[tok][d0] = xs;
            }
            if (lane == 0) {
                scratch[896 + tok] = rs;
                scratch[904 + tok] = -mu * rs;
            }
        }
    }
    bar_lds();

    // ---------------- GEMM1: ypart = x_bf16 @ (gamma*w_down)^T, K split in halves ----------------
    // A rows m>=8 read duplicate token rows (m&7): finite garbage, C rows 8..15 discarded.
#pragma unroll
    for (int rep = 0; rep < 2; ++rep) {
        int jid = w + rep * 4;
        if (jid < 6) {
            int cb = jid % 3, kh = jid / 3;
            float4a acc = {0.f, 0.f, 0.f, 0.f};
            const short* bptr = wdn_b + ((cb * 32 + kh * 16) * 64 + lane) * 8;
            const short* aptr = &xsh[m & 7][kh * 512 + q * 8];
#pragma unroll
            for (int kt = 0; kt < 16; ++kt) {
                short8 a = *(const short8*)(aptr + kt * 32);
                short8 b = *(const short8*)(bptr + kt * 512);
                acc = __builtin_amdgcn_mfma_f32_16x16x32_bf16(a, b, acc, 0, 0, 0);
            }
            if (q < 2) {   // C rows q*4+i < 8 are valid tokens
#pragma unroll
                for (int i = 0; i < 4; ++i)
                    scratch[kh * 384 + (q * 4 + i) * 48 + cb * 16 + m] = acc[i];
            }
        }
    }
    bar_lds();

    // ---------------- Middle (fp32 VALU) ----------------
    // A: K-half reduce + LN affine correction + exact GELU (in place in ypart[0])
#pragma unroll
    for (int k = 0; k < 2; ++k) {
        int it = tid + k * 256;               // 384 = 8 tok x 48 r
        if (it < 384) {
            int tt = it / 48, r = it - tt * 48;
            float s = scratch[it] + scratch[384 + it];
            float y = fmaf(scratch[896 + tt], s, fmaf(scratch[904 + tt], c12[r], c12[48 + r]));
            scratch[it] = gelu_exact(y);
        }
    }
    bar_lds();
    // B: multivectors + grade scale + scalar bias -> mvbuf (scratch[768..895])
    if (tid < 128) {
        int tt = tid >> 4, j = tid & 15;
        float acc = 0.f;
#pragma unroll 8
        for (int r = 0; r < 48; ++r) acc = fmaf(w_to_mv[j * 48 + r], scratch[tt * 48 + r], acc);
        int g = (j == 0) ? 0 : (j < 5) ? 1 : (j < 11) ? 2 : (j < 15) ? 3 : 4;
        acc *= w_equi[g];
        if (j == 0) acc += b_equi[0];
        scratch[768 + tt * 16 + j] = acc;
    }
    bar_lds();
    // C: z = gelu(mv @ w_from_mv^T) -> zbuf in GEMM2 A-fragment order (K padded 48->64)
#pragma unroll
    for (int k = 0; k < 2; ++k) {
        int it = tid + k * 256;
        if (it < 384) {
            int tt = it / 48, r = it - tt * 48;
            float acc = 0.f;
#pragma unroll
            for (int j = 0; j < 16; ++j)
                acc = fmaf(w_from_mv[r * 16 + j], scratch[768 + tt * 16 + j], acc);
            float z = gelu_exact(acc);
            int kt = r >> 5, qq = (r >> 3) & 3, jj = r & 7;
            zbuf[kt * 512 + (qq * 16 + tt) * 8 + jj] = f2bf(z);
        }
    }
    zbuf[768 + tid] = 0;                      // K padding r in [48,64): zeros for all valid rows
    bar_lds();

    // ---------------- GEMM2 + epilogue: out = x + scale * (z @ w_up^T) ----------------
    const float scale = scale_p[0];
    short8 a0 = *(const short8*)&zbuf[lane * 8];
    short8 a1 = *(const short8*)&zbuf[512 + lane * 8];
    long rowbase = (token0 + q * 4) * D;
#pragma unroll 4
    for (int cc = 0; cc < 16; ++cc) {
        int cb = w * 16 + cc;
        short8 b0 = *(const short8*)(wup_b + (cb * 2 + 0) * 512 + lane * 8);
        short8 b1 = *(const short8*)(wup_b + (cb * 2 + 1) * 512 + lane * 8);
        float4a acc = {0.f, 0.f, 0.f, 0.f};
        acc = __builtin_amdgcn_mfma_f32_16x16x32_bf16(a0, b0, acc, 0, 0, 0);
        acc = __builtin_amdgcn_mfma_f32_16x16x32_bf16(a1, b1, acc, 0, 0, 0);
        int d = cb * 16 + m;
        if (q < 2) {   // tokens q*4+i < 8
#pragma unroll
            for (int i = 0; i < 4; ++i) {
                int tok = q * 4 + i;
                float xv = bf2f(xsh[tok][d]);
                out[rowbase + (long)i * D + d] = fmaf(scale, acc[i], xv);
            }
        }
    }
}

extern "C" void kernel_launch(void* const* d_in, const int* in_sizes, int n_in,
                              void* d_out, int out_size, void* d_ws, size_t ws_size,
                              hipStream_t stream) {
    const float* x         = (const float*)d_in[0];
    const float* gamma     = (const float*)d_in[1];
    const float* beta      = (const float*)d_in[2];
    const float* w_down    = (const float*)d_in[3];
    const float* w_to_mv   = (const float*)d_in[4];
    const float* w_equi    = (const float*)d_in[5];
    const float* b_equi    = (const float*)d_in[6];
    const float* w_from_mv = (const float*)d_in[7];
    const float* w_up      = (const float*)d_in[8];
    const float* scale_p   = (const float*)d_in[9];

    short* wdn_b = (short*)d_ws;               // 49152 bf16
    short* wup_b = wdn_b + 49152;              // 65536 bf16 (K padded to 64)
    float* c12   = (float*)(wup_b + 65536);    // 96 fp32

    prep_weights<<<496, 256, 0, stream>>>(w_down, w_up, gamma, beta, wdn_b, wup_b, c12);
    adapter_main<<<NBLK, 256, 0, stream>>>(
        x, w_to_mv, w_equi, b_equi, w_from_mv, scale_p,
        wdn_b, wup_b, c12, (float*)d_out);
}

// Round 3
// 264.519 us; speedup vs baseline: 1.0713x; 1.0493x over previous
//
#include <hip/hip_runtime.h>
#include <hip/hip_bf16.h>

// LorentzEquivariantAdapter fused kernel, MI355X gfx950. Round 5.
// Post-mortem R4: occupancy 80% made it SLOWER (109 vs 94 us). Per-block fixed
// costs dominate: each block reads all 224KB of weights from L2, crosses 6
// barrier-fenced phases each with an exposed cold L2-load burst ("memory"
// fences forbid hoisting). Smaller tiles double fixed cost per token.
// R5: amortize the other way.
//  - 32-tok / 512-thread blocks, 1024 blocks, 2 blocks/CU (74.5KB LDS):
//    barriers per token cut 2.4x; GEMM1 full-K per wave (no K-half reduce,
//    single ypart buffer); GEMM2 B-frags reused across both M-tiles (wup_b
//    L2 traffic per token halved).
//  - middle-B w_to_mv dot FULLY unrolled: 48 loads in 1 batch (was 6 batches
//    of 8 -> 6 serial L2 latencies).
//  - GEMM2's 16 B-fragment loads manually hoisted above the pre-GEMM2
//    barrier (independent of z; compiler can't cross the asm fence).
//  - non-draining barriers (lgkmcnt only) kept from R4.

typedef __attribute__((ext_vector_type(8))) short short8;   // 8 bf16 = one MFMA A/B fragment
typedef __attribute__((ext_vector_type(4))) short short4b;  // 4 bf16 = 8B store
typedef __attribute__((ext_vector_type(4))) float float4a;  // MFMA accumulator

#define NTOK 32768
#define D 1024
#define TOK 32
#define NBLK (NTOK / TOK)   // 1024

__device__ __forceinline__ short f2bf(float x) {
    unsigned u = __float_as_uint(x);
    unsigned r = u + 0x7FFFu + ((u >> 16) & 1u);   // RNE
    return (short)(r >> 16);
}
__device__ __forceinline__ float bf2f(short s) {
    return __uint_as_float(((unsigned)(unsigned short)s) << 16);
}
__device__ __forceinline__ float gelu_exact(float v) {
    return 0.5f * v * (1.0f + erff(v * 0.70710678118654752f));
}

// Non-draining workgroup barrier: orders LDS (lgkmcnt) but leaves global
// loads/stores (vmcnt) in flight. Safe: all cross-wave traffic is LDS-only;
// global accesses are thread-private loads, read-only weights, or
// write-once outputs never re-read.
__device__ __forceinline__ void bar_lds() {
    asm volatile("s_waitcnt lgkmcnt(0)" ::: "memory");
    __builtin_amdgcn_s_barrier();
    asm volatile("" ::: "memory");
}

// ---- weight prep (unchanged layouts) ----
// blocks [0,192):   wdn_b = bf16(gamma[d] * w_down[r][d]) in MFMA B-fragment order
// blocks [192,448): wup_b = bf16(w_up[d][r]) in MFMA B-fragment order, K padded 48->64
// blocks [448,496): c12[r] = sum_d gamma[d]*w_down[r][d];  c12[48+r] = sum_d beta[d]*w_down[r][d]
__global__ void prep_weights(const float* __restrict__ wdn_f, const float* __restrict__ wup_f,
                             const float* __restrict__ gamma, const float* __restrict__ beta,
                             short* __restrict__ wdn_b, short* __restrict__ wup_b,
                             float* __restrict__ c12) {
    int blk = blockIdx.x;
    int tid = threadIdx.x;
    if (blk < 192) {
        int o = blk * 256 + tid;
        int j = o & 7, lane = (o >> 3) & 63, kt = (o >> 9) & 31, cb = o >> 14;
        int r = cb * 16 + (lane & 15);
        int d = kt * 32 + (lane >> 4) * 8 + j;
        wdn_b[o] = f2bf(wdn_f[r * 1024 + d] * gamma[d]);
    } else if (blk < 448) {
        int o2 = (blk - 192) * 256 + tid;
        int j = o2 & 7, lane = (o2 >> 3) & 63, kt = (o2 >> 9) & 1, cb = o2 >> 10;
        int dcol = cb * 16 + (lane & 15);
        int r = kt * 32 + (lane >> 4) * 8 + j;
        wup_b[o2] = (r < 48) ? f2bf(wup_f[dcol * 48 + r]) : (short)0;
    } else {
        int r = blk - 448;                       // 0..47
        float a = 0.f, b = 0.f;
#pragma unroll
        for (int i = 0; i < 4; ++i) {
            int d = tid + 256 * i;
            float wv = wdn_f[r * 1024 + d];
            a = fmaf(wv, gamma[d], a);
            b = fmaf(wv, beta[d], b);
        }
#pragma unroll
        for (int off = 32; off; off >>= 1) {
            a += __shfl_xor(a, off);
            b += __shfl_xor(b, off);
        }
        __shared__ float red[8];
        int lane = tid & 63, w = tid >> 6;
        if (lane == 0) { red[w] = a; red[4 + w] = b; }
        __syncthreads();
        if (tid == 0) {
            c12[r]      = red[0] + red[1] + red[2] + red[3];
            c12[48 + r] = red[4] + red[5] + red[6] + red[7];
        }
    }
}

__launch_bounds__(512, 4)
__global__ void adapter_main(const float* __restrict__ x, const float* __restrict__ w_to_mv,
                             const float* __restrict__ w_equi, const float* __restrict__ b_equi,
                             const float* __restrict__ w_from_mv, const float* __restrict__ scale_p,
                             const short* __restrict__ wdn_b, const short* __restrict__ wup_b,
                             const float* __restrict__ c12, float* __restrict__ out) {
    // LDS total = 66048 + 8448 = 74496 B -> 2 blocks/CU (148,992 <= 163,840)
    __shared__ __align__(16) short xsh[TOK][1032];  // x as bf16, +8 shorts pad (16B-aligned rows)
    __shared__ __align__(16) float scratch[2112];
    // scratch layout (floats, phase-aliased):
    //   [0..1535]    y[tok][r] (GEMM1 out, full K) -> gelu(y) in place
    //                -> zbuf shorts [0..2047]: z in GEMM2 A-frag order,
    //                   layout mt*1024 + kt*512 + (qq*16+ttl)*8 + jj
    //   [1536..2047] mvbuf[tok][16]
    //   [2048..2079] rs[tok]     [2080..2111]  -mu*rs[tok]
    short* zbuf = (short*)scratch;

    const int tid  = threadIdx.x;
    const int lane = tid & 63;
    const int w    = tid >> 6;          // wave id 0..7
    const int q    = lane >> 4;         // MFMA quad
    const int m    = lane & 15;         // MFMA row/col within tile
    const long token0 = (long)blockIdx.x * TOK;

    // ---------------- Phase 0: load x (16 float4/thread), stats, x->bf16 LDS ----------------
    {
        const float4* xr = (const float4*)(x + token0 * D);
        float4 v[16];
#pragma unroll
        for (int t = 0; t < 4; ++t)
#pragma unroll
            for (int i = 0; i < 4; ++i)
                v[t * 4 + i] = xr[(w * 4 + t) * 256 + lane + 64 * i];

#pragma unroll
        for (int t = 0; t < 4; ++t) {
            int tok = w * 4 + t;
            float s1 = 0.f, s2 = 0.f;
#pragma unroll
            for (int i = 0; i < 4; ++i) {
                float4 vv = v[t * 4 + i];
                s1 += vv.x + vv.y + vv.z + vv.w;
                s2 += vv.x * vv.x + vv.y * vv.y + vv.z * vv.z + vv.w * vv.w;
            }
#pragma unroll
            for (int off = 32; off; off >>= 1) {
                s1 += __shfl_xor(s1, off);
                s2 += __shfl_xor(s2, off);
            }
            float mu  = s1 * (1.0f / 1024.0f);
            float var = fmaf(-mu, mu, s2 * (1.0f / 1024.0f));
            float rs  = rsqrtf(var + 1e-5f);
#pragma unroll
            for (int i = 0; i < 4; ++i) {
                int d0 = 4 * lane + 256 * i;
                float4 vv = v[t * 4 + i];
                short4b xs = {f2bf(vv.x), f2bf(vv.y), f2bf(vv.z), f2bf(vv.w)};
                *(short4b*)&xsh[tok][d0] = xs;
            }
            if (lane == 0) {
                scratch[2048 + tok] = rs;
                scratch[2080 + tok] = -mu * rs;
            }
        }
    }
    bar_lds();

    // ---------------- GEMM1: y = x_bf16 @ (gamma*w_down)^T, full K per wave ----------------
    // 6 jobs (mt in [0,2) x cb in [0,3)) over 8 waves; waves 6,7 idle here.
    if (w < 6) {
        int mt = w & 1, cb = w >> 1;
        float4a acc = {0.f, 0.f, 0.f, 0.f};
        const short* bptr = wdn_b + cb * 16384 + lane * 8;
        const short* aptr = &xsh[mt * 16 + m][q * 8];
#pragma unroll
        for (int kt = 0; kt < 32; ++kt) {
            short8 a = *(const short8*)(aptr + kt * 32);
            short8 b = *(const short8*)(bptr + kt * 512);
            acc = __builtin_amdgcn_mfma_f32_16x16x32_bf16(a, b, acc, 0, 0, 0);
        }
#pragma unroll
        for (int i = 0; i < 4; ++i)
            scratch[(mt * 16 + q * 4 + i) * 48 + cb * 16 + m] = acc[i];
    }
    bar_lds();

    // ---------------- Middle (fp32 VALU) ----------------
    // A: LN affine correction + exact GELU (in place; no K-half reduce anymore)
#pragma unroll
    for (int k = 0; k < 3; ++k) {
        int it = tid + k * 512;               // 1536 = 32 tok x 48 r
        int tt = it / 48, r = it - tt * 48;
        float y = fmaf(scratch[2048 + tt], scratch[it],
                       fmaf(scratch[2080 + tt], c12[r], c12[48 + r]));
        scratch[it] = gelu_exact(y);
    }
    bar_lds();
    // B: multivectors + grade scale + scalar bias -> mvbuf. FULL unroll: all 48
    // w_to_mv loads issue as one batch (one L2 latency, not six).
    {
        int tt = tid >> 4, j = tid & 15;      // 32 tok x 16 j = 512 threads
        float acc = 0.f;
#pragma unroll
        for (int r = 0; r < 48; ++r) acc = fmaf(w_to_mv[j * 48 + r], scratch[tt * 48 + r], acc);
        int g = (j == 0) ? 0 : (j < 5) ? 1 : (j < 11) ? 2 : (j < 15) ? 3 : 4;
        acc *= w_equi[g];
        if (j == 0) acc += b_equi[0];
        scratch[1536 + tt * 16 + j] = acc;
    }
    bar_lds();
    // C: z = gelu(mv @ w_from_mv^T) -> zbuf in GEMM2 A-fragment order (K padded 48->64)
#pragma unroll
    for (int k = 0; k < 3; ++k) {
        int it = tid + k * 512;
        int tt = it / 48, r = it - tt * 48;
        float acc = 0.f;
#pragma unroll
        for (int j = 0; j < 16; ++j)
            acc = fmaf(w_from_mv[r * 16 + j], scratch[1536 + tt * 16 + j], acc);
        float z = gelu_exact(acc);
        int mt = tt >> 4, ttl = tt & 15;
        int kt = r >> 5, qq = (r >> 3) & 3, jj = r & 7;
        zbuf[mt * 1024 + kt * 512 + (qq * 16 + ttl) * 8 + jj] = f2bf(z);
    }
    // K padding: kt=1, qq in {2,3} (k-local >= 16, i.e. r >= 64 region) zeros
    zbuf[(tid >> 8) * 1024 + 768 + (tid & 255)] = 0;

    // GEMM2 B-fragment preload: independent of zbuf; issue BEFORE the barrier
    // so the 16 L2 loads overlap the barrier wait + A-frag LDS reads.
    short8 b0[8], b1[8];
#pragma unroll
    for (int c = 0; c < 8; ++c) {
        int cb = w * 8 + c;
        b0[c] = *(const short8*)(wup_b + (cb * 2 + 0) * 512 + lane * 8);
        b1[c] = *(const short8*)(wup_b + (cb * 2 + 1) * 512 + lane * 8);
    }
    bar_lds();

    // ---------------- GEMM2 + epilogue: out = x + scale * (z @ w_up^T) ----------------
    // Wave w covers cols [w*128, w*128+128); B-frags reused across both M-tiles.
    const float scale = scale_p[0];
    short8 a00 = *(const short8*)&zbuf[           lane * 8];   // mt0, kt0
    short8 a01 = *(const short8*)&zbuf[ 512 +     lane * 8];   // mt0, kt1
    short8 a10 = *(const short8*)&zbuf[1024 +     lane * 8];   // mt1, kt0
    short8 a11 = *(const short8*)&zbuf[1536 +     lane * 8];   // mt1, kt1
#pragma unroll
    for (int c = 0; c < 8; ++c) {
        int cb = w * 8 + c;
        int d = cb * 16 + m;
        float4a acc0 = {0.f, 0.f, 0.f, 0.f};
        acc0 = __builtin_amdgcn_mfma_f32_16x16x32_bf16(a00, b0[c], acc0, 0, 0, 0);
        acc0 = __builtin_amdgcn_mfma_f32_16x16x32_bf16(a01, b1[c], acc0, 0, 0, 0);
        float4a acc1 = {0.f, 0.f, 0.f, 0.f};
        acc1 = __builtin_amdgcn_mfma_f32_16x16x32_bf16(a10, b0[c], acc1, 0, 0, 0);
        acc1 = __builtin_amdgcn_mfma_f32_16x16x32_bf16(a11, b1[c], acc1, 0, 0, 0);
#pragma unroll
        for (int i = 0; i < 4; ++i) {
            int t0 = q * 4 + i;               // token (local) in M-tile 0
            out[(token0 + t0) * D + d]      = fmaf(scale, acc0[i], bf2f(xsh[t0][d]));
            out[(token0 + 16 + t0) * D + d] = fmaf(scale, acc1[i], bf2f(xsh[16 + t0][d]));
        }
    }
}

extern "C" void kernel_launch(void* const* d_in, const int* in_sizes, int n_in,
                              void* d_out, int out_size, void* d_ws, size_t ws_size,
                              hipStream_t stream) {
    const float* x         = (const float*)d_in[0];
    const float* gamma     = (const float*)d_in[1];
    const float* beta      = (const float*)d_in[2];
    const float* w_down    = (const float*)d_in[3];
    const float* w_to_mv   = (const float*)d_in[4];
    const float* w_equi    = (const float*)d_in[5];
    const float* b_equi    = (const float*)d_in[6];
    const float* w_from_mv = (const float*)d_in[7];
    const float* w_up      = (const float*)d_in[8];
    const float* scale_p   = (const float*)d_in[9];

    short* wdn_b = (short*)d_ws;               // 49152 bf16
    short* wup_b = wdn_b + 49152;              // 65536 bf16 (K padded to 64)
    float* c12   = (float*)(wup_b + 65536);    // 96 fp32

    prep_weights<<<496, 256, 0, stream>>>(w_down, w_up, gamma, beta, wdn_b, wup_b, c12);
    adapter_main<<<NBLK, 512, 0, stream>>>(
        x, w_to_mv, w_equi, b_equi, w_from_mv, scale_p,
        wdn_b, wup_b, c12, (float*)d_out);
}